// Round 13
// baseline (146.584 us; speedup 1.0000x reference)
//
#include <hip/hip_runtime.h>
#include <math.h>
#include <stdint.h>

#define T_TOTAL 2048
#define NB 16
#define D 256
#define T0 1696      // h buffer covers t in [1696, 2047]
#define TBUF 352
#define TSKIP 1952   // output rows t in [1952, 2047]
#define LOUT 96

typedef __bf16 bf16x8 __attribute__((ext_vector_type(8)));
typedef __bf16 bf16x4v __attribute__((ext_vector_type(4)));
typedef float f32x4 __attribute__((ext_vector_type(4)));

__device__ __forceinline__ void gload_lds16(const void* src, void* lds_dst) {
    auto g = (const __attribute__((address_space(1))) void*)(uintptr_t)src;
    auto l = (__attribute__((address_space(3))) void*)(uintptr_t)(
                 (uint32_t)(uintptr_t)lds_dst);
    __builtin_amdgcn_global_load_lds(g, l, 16, 0, 0);
}

// ---------------- fused weight prep + up-projection + vW (one dispatch)
// vW[l][ci] = sum_c skip_w[l][256+c][ci] * loc_W[c]   (f32, collapses skip path)
__global__ __launch_bounds__(256) void prep_up(
    const float* __restrict__ dil_w, const float* __restrict__ skip_w,
    const float* __restrict__ x_lag, const float* __restrict__ x_cov,
    const float* __restrict__ up_W, const float* __restrict__ up_b,
    const float* __restrict__ loc_W,
    __bf16* __restrict__ wT, __bf16* __restrict__ w2,
    float* __restrict__ hf, __bf16* __restrict__ hb,
    float* __restrict__ vW)
{
    const int g0 = blockIdx.x * 256 + threadIdx.x;
    const int NT = 2048 * 256;

    for (int u = g0; u < 8 * 512 * 32; u += NT) {
        int j = u & 31;
        int cog = u >> 5;
        const float* src = dil_w + ((size_t)cog << 9) + (j << 4);
        float4 a = *(const float4*)(src);
        float4 b = *(const float4*)(src + 4);
        float4 c = *(const float4*)(src + 8);
        float4 d = *(const float4*)(src + 12);
        bf16x8 t0 = {(__bf16)a.x, (__bf16)a.z, (__bf16)b.x, (__bf16)b.z,
                     (__bf16)c.x, (__bf16)c.z, (__bf16)d.x, (__bf16)d.z};
        bf16x8 t1 = {(__bf16)a.y, (__bf16)a.w, (__bf16)b.y, (__bf16)b.w,
                     (__bf16)c.y, (__bf16)c.w, (__bf16)d.y, (__bf16)d.w};
        *(bf16x8*)(wT + ((size_t)cog << 9) + (j << 3)) = t0;
        *(bf16x8*)(wT + ((size_t)cog << 9) + 256 + (j << 3)) = t1;
    }
    for (int u = g0; u < 8 * 512 * 32; u += NT) {
        const float* src = skip_w + ((size_t)u << 3);
        float4 a = *(const float4*)(src);
        float4 b = *(const float4*)(src + 4);
        bf16x8 v = {(__bf16)a.x, (__bf16)a.y, (__bf16)a.z, (__bf16)a.w,
                    (__bf16)b.x, (__bf16)b.y, (__bf16)b.z, (__bf16)b.w};
        *(bf16x8*)(w2 + ((size_t)u << 3)) = v;
    }
    for (int u = g0; u < TBUF * NB * D; u += NT) {
        int row = u >> 8, c = u & 255;
        int tt = row >> 4, b = row & 15, t = T0 + tt;
        float acc = up_b[c] + x_lag[t * NB + b] * up_W[c];
        const float* cov = &x_cov[(t * NB + b) * 7];
        #pragma unroll
        for (int j = 0; j < 7; ++j)
            acc += cov[j] * up_W[(j + 1) * D + c];
        hf[u] = acc;
        hb[u] = (__bf16)acc;
    }
    for (int u = g0; u < 2048; u += NT) {
        int ly = u >> 8, ci = u & 255;
        float acc = 0.f;
        #pragma unroll 4
        for (int c = 0; c < 256; ++c)
            acc += skip_w[(((ly << 9) + 256 + c) << 8) + ci] * loc_W[c];
        vW[u] = acc;
    }
}

// ---------------- GEMM1 narrow: grid (mt,8), BN=32, 16KB/buf -> 4 blocks/CU
// tail rows additionally saved to gsv (consumed by final_v2)
__global__ __launch_bounds__(512, 4) void gate_n32(
    const __bf16* __restrict__ hb, __bf16* __restrict__ gated,
    const __bf16* __restrict__ wTl, const float* __restrict__ gbias,
    __bf16* __restrict__ gsv, int do_save,
    int tb, int dil, int M)
{
    __shared__ __align__(16) unsigned char lds[32768];
    const int tid = threadIdx.x;
    const int lane = tid & 63, wid = tid >> 6;
    const int wm = wid >> 1, wn = wid & 1;
    const int l15 = lane & 15, l4 = lane >> 4;
    const int m0 = blockIdx.x << 6;
    const int cb = blockIdx.y << 5;               // 0..224
    const int arow = (wid << 3) + (lane >> 3);    // 0..63
    const int ach = lane & 7;
    const int aswz = (ach ^ (arow & 7)) << 3;
    const int bwid = wid & 3, bhalf = wid >> 2;   // 4 waves per B half
    const int brow = (bwid << 3) + (lane >> 3);   // 0..31
    const int bswz = (ach ^ (brow & 7)) << 3;
    const int roff1 = (tb - T0) * 16;
    const int roff0 = roff1 - dil * 16;

    f32x4 accf = {}, accg = {};

    auto stage = [&](int t, int buf) {
        const int k0 = t << 6;
        const int ci0 = k0 & 255;
        const int roff = (t < 4) ? roff0 : roff1;
        unsigned char* base = lds + buf * 16384;
        int m = m0 + arow; if (m >= M) m = M - 1;
        gload_lds16(hb + (size_t)(m + roff) * 256 + ci0 + aswz,
                    base + (wid << 10));
        gload_lds16(wTl + (size_t)(cb + bhalf * 256 + brow) * 512 + k0 + bswz,
                    base + 8192 + (bhalf << 12) + (bwid << 10));
    };

    stage(0, 0);
    for (int t = 0; t < 8; ++t) {
        const int buf = t & 1;
        if (t < 7) {
            stage(t + 1, buf ^ 1);
            asm volatile("s_waitcnt vmcnt(2)" ::: "memory");
        } else {
            asm volatile("s_waitcnt vmcnt(0)" ::: "memory");
        }
        __builtin_amdgcn_s_barrier();
        const unsigned char* base = lds + buf * 16384;
        __builtin_amdgcn_s_setprio(1);
        #pragma unroll
        for (int ks = 0; ks < 2; ++ks) {
            const int kb = (ks << 6) + (l4 << 4);
            int r = (wm << 4) + l15;
            bf16x8 av = *(const bf16x8*)(base + r * 128 + (kb ^ ((r & 7) << 4)));
            int n = (wn << 4) + l15;
            int o = n * 128 + (kb ^ ((n & 7) << 4));
            bf16x8 bfv = *(const bf16x8*)(base + 8192 + o);
            bf16x8 bgv = *(const bf16x8*)(base + 12288 + o);
            accf = __builtin_amdgcn_mfma_f32_16x16x32_bf16(av, bfv, accf, 0, 0, 0);
            accg = __builtin_amdgcn_mfma_f32_16x16x32_bf16(av, bgv, accg, 0, 0, 0);
        }
        __builtin_amdgcn_s_setprio(0);
        __builtin_amdgcn_s_barrier();
    }

    {
        const int ms0 = (TSKIP - tb) * 16;
        const int soff = (tb - TSKIP) * 16;
        int c = cb + (wn << 4) + l15;
        float bfb = gbias[c], bgb = gbias[c + 256];
        #pragma unroll
        for (int r = 0; r < 4; ++r) {
            int m = m0 + (wm << 4) + (l4 << 2) + r;
            if (m < M) {
                float fv = accf[r] + bfb;
                float gv = accg[r] + bgb;
                float th = 2.0f / (1.0f + __expf(-2.0f * fv)) - 1.0f;
                float sg = 1.0f / (1.0f + __expf(-gv));
                __bf16 val = (__bf16)(th * sg);
                gated[(size_t)m * 256 + c] = val;
                if (do_save && m >= ms0)
                    gsv[(size_t)(m + soff) * 256 + c] = val;
            }
        }
    }
}

// ---------------- GEMM2 h-only: grid (mt,8), BN=32, 12KB/buf
// h += gated @ w2h^T + bh   (skip path handled algebraically in final_v2)
__global__ __launch_bounds__(512, 4) void skip_h(
    const __bf16* __restrict__ gated, const __bf16* __restrict__ w2l,
    float* __restrict__ hf, __bf16* __restrict__ hb,
    const float* __restrict__ sbias, int tb, int M)
{
    __shared__ __align__(16) unsigned char lds[24576];
    const int tid = threadIdx.x;
    const int lane = tid & 63, wid = tid >> 6;
    const int wm = wid >> 1, wn = wid & 1;
    const int l15 = lane & 15, l4 = lane >> 4;
    const int m0 = blockIdx.x << 6;
    const int cb = blockIdx.y << 5;
    const int arow = (wid << 3) + (lane >> 3);
    const int ach = lane & 7;
    const int aswz = (ach ^ (arow & 7)) << 3;
    const int brow = (wid << 3) + (lane >> 3);    // valid for wid<4
    const int bswz = (ach ^ (brow & 7)) << 3;
    const int roff1 = (tb - T0) * 16;

    f32x4 acch = {};

    auto stage = [&](int t, int buf) {
        const int k0 = t << 6;
        unsigned char* base = lds + buf * 12288;
        int m = m0 + arow; if (m >= M) m = M - 1;
        gload_lds16(gated + (size_t)m * 256 + k0 + aswz,
                    base + (wid << 10));
        if (wid < 4)
            gload_lds16(w2l + (size_t)(cb + brow) * 256 + k0 + bswz,
                        base + 8192 + (wid << 10));
    };

    stage(0, 0);
    for (int t = 0; t < 4; ++t) {
        const int buf = t & 1;
        if (t < 3) {
            stage(t + 1, buf ^ 1);
            if (wid < 4) { asm volatile("s_waitcnt vmcnt(2)" ::: "memory"); }
            else         { asm volatile("s_waitcnt vmcnt(1)" ::: "memory"); }
        } else {
            asm volatile("s_waitcnt vmcnt(0)" ::: "memory");
        }
        __builtin_amdgcn_s_barrier();
        const unsigned char* base = lds + buf * 12288;
        __builtin_amdgcn_s_setprio(1);
        #pragma unroll
        for (int ks = 0; ks < 2; ++ks) {
            const int kb = (ks << 6) + (l4 << 4);
            int r = (wm << 4) + l15;
            bf16x8 av = *(const bf16x8*)(base + r * 128 + (kb ^ ((r & 7) << 4)));
            int n = (wn << 4) + l15;
            int o = n * 128 + (kb ^ ((n & 7) << 4));
            bf16x8 bhv = *(const bf16x8*)(base + 8192 + o);
            acch = __builtin_amdgcn_mfma_f32_16x16x32_bf16(av, bhv, acch, 0, 0, 0);
        }
        __builtin_amdgcn_s_setprio(0);
        __builtin_amdgcn_s_barrier();
    }

    {
        int c = cb + (wn << 4) + l15;
        float bhb = sbias[c];
        #pragma unroll
        for (int r = 0; r < 4; ++r) {
            int m = m0 + (wm << 4) + (l4 << 2) + r;
            if (m < M) {
                size_t hi = (size_t)(m + roff1) * 256 + c;
                float hv = hf[hi] + acch[r] + bhb;
                hf[hi] = hv;
                hb[hi] = (__bf16)hv;
            }
        }
    }
}

// ---------------- final: out = (sum_l gated_l . vW_l + Cs + loc_b)*projW + proj_b
__global__ __launch_bounds__(256) void final_v2(
    const __bf16* __restrict__ gsave, const __bf16* __restrict__ gated,
    const float* __restrict__ vW, const float* __restrict__ skip_b,
    const float* __restrict__ loc_W, const float* __restrict__ loc_b,
    const float* __restrict__ proj_W, const float* __restrict__ proj_b,
    float* __restrict__ out)
{
    int tid = threadIdx.x;
    int wid = tid >> 6, lane = tid & 63;
    int o = blockIdx.x * 4 + wid;        // o = (t - TSKIP)*16 + b
    float acc = 0.f;
    #pragma unroll
    for (int ly = 0; ly < 8; ++ly) {
        const __bf16* g = (ly < 7) ? gsave + (((size_t)ly * 1536 + o) << 8)
                                   : gated + ((size_t)o << 8);
        bf16x4v gv = *(const bf16x4v*)(g + (lane << 2));
        float4 vw = *(const float4*)(vW + (ly << 8) + (lane << 2));
        acc += (float)gv[0] * vw.x + (float)gv[1] * vw.y
             + (float)gv[2] * vw.z + (float)gv[3] * vw.w;
    }
    // skip-bias contribution: sum_{ly,c} skip_b[ly][256+c]*loc_W[c]
    #pragma unroll
    for (int j = 0; j < 32; ++j) {
        int idx = lane + (j << 6);
        int ly = idx >> 8, c = idx & 255;
        acc += skip_b[(ly << 9) + 256 + c] * loc_W[c];
    }
    #pragma unroll
    for (int off = 32; off; off >>= 1) acc += __shfl_down(acc, off);
    if (lane == 0) {
        int l = o >> 4, b = o & 15;
        out[b * LOUT + l] = (acc + loc_b[0]) * proj_W[0] + proj_b[0];
    }
}

extern "C" void kernel_launch(void* const* d_in, const int* in_sizes, int n_in,
                              void* d_out, int out_size, void* d_ws, size_t ws_size,
                              hipStream_t stream)
{
    const float* x_lag  = (const float*)d_in[0];
    const float* x_cov  = (const float*)d_in[1];
    const float* up_W   = (const float*)d_in[2];
    const float* up_b   = (const float*)d_in[3];
    const float* dil_w  = (const float*)d_in[4];
    const float* dil_b  = (const float*)d_in[5];
    const float* skip_w = (const float*)d_in[6];
    const float* skip_b = (const float*)d_in[7];
    const float* loc_W  = (const float*)d_in[8];
    const float* loc_b  = (const float*)d_in[9];
    const float* proj_W = (const float*)d_in[10];
    const float* proj_b = (const float*)d_in[11];
    float* out = (float*)d_out;

    unsigned char* ws = (unsigned char*)d_ws;
    float*  hf    = (float*)ws;                               // 5,767,168
    __bf16* hb    = (__bf16*)(ws + 5767168);                  // 2,883,584
    __bf16* gated = (__bf16*)(ws + 8650752);                  // 2,883,584
    __bf16* gsave = (__bf16*)(ws + 11534336);                 // 7*1536*256*2 = 5,505,024
    __bf16* wT    = (__bf16*)(ws + 17039360);                 // 4,194,304
    __bf16* w2    = (__bf16*)(ws + 21233664);                 // 2,097,152
    float*  vW    = (float*)(ws + 23330816);                  // 8,192

    hipLaunchKernelGGL(prep_up, dim3(2048), dim3(256), 0, stream,
                       dil_w, skip_w, x_lag, x_cov, up_W, up_b, loc_W,
                       wT, w2, hf, hb, vW);

    for (int i = 0; i < 8; ++i) {
        int dil = 1 << i;
        int tb  = T0 + 2 * dil;
        int M   = (T_TOTAL - tb) * NB;
        int mt  = (M + 63) >> 6;
        const __bf16* wTl = wT + (size_t)i * 512 * 512;
        const __bf16* w2l = w2 + (size_t)i * 512 * 256;
        const float* gb = dil_b + (size_t)i * 512;
        const float* sb = skip_b + (size_t)i * 512;

        hipLaunchKernelGGL(gate_n32, dim3(mt, 8), dim3(512), 0, stream,
                           hb, gated, wTl, gb,
                           gsave + (size_t)i * 1536 * 256, i < 7 ? 1 : 0,
                           tb, dil, M);
        if (i < 7)
            hipLaunchKernelGGL(skip_h, dim3(mt, 8), dim3(512), 0, stream,
                               gated, w2l, hf, hb, sb, tb, M);
    }
    hipLaunchKernelGGL(final_v2, dim3(LOUT * NB / 4), dim3(256), 0, stream,
                       gsave, gated, vW, skip_b, loc_W, loc_b, proj_W, proj_b,
                       out);
}

// Round 14
// 131.279 us; speedup vs baseline: 1.1166x; 1.1166x over previous
//
#include <hip/hip_runtime.h>
#include <math.h>
#include <stdint.h>

#define T_TOTAL 2048
#define NB 16
#define D 256
#define T0 1696      // h buffer covers t in [1696, 2047]
#define TBUF 352
#define TSKIP 1952   // output rows t in [1952, 2047]
#define LOUT 96

typedef __bf16 bf16x8 __attribute__((ext_vector_type(8)));
typedef __bf16 bf16x4v __attribute__((ext_vector_type(4)));
typedef float f32x4 __attribute__((ext_vector_type(4)));

__device__ __forceinline__ void gload_lds16(const void* src, void* lds_dst) {
    auto g = (const __attribute__((address_space(1))) void*)(uintptr_t)src;
    auto l = (__attribute__((address_space(3))) void*)(uintptr_t)(
                 (uint32_t)(uintptr_t)lds_dst);
    __builtin_amdgcn_global_load_lds(g, l, 16, 0, 0);
}

// ---------------- fused weight prep + up-projection + vW partials
// vWp[part][ly][ci] = sum_{c in part*32..} skip_w[ly][256+c][ci] * loc_W[c]
__global__ __launch_bounds__(256) void prep_up(
    const float* __restrict__ dil_w, const float* __restrict__ skip_w,
    const float* __restrict__ x_lag, const float* __restrict__ x_cov,
    const float* __restrict__ up_W, const float* __restrict__ up_b,
    const float* __restrict__ loc_W,
    __bf16* __restrict__ wT, __bf16* __restrict__ w2,
    float* __restrict__ hf, __bf16* __restrict__ hb,
    float* __restrict__ vWp)
{
    const int g0 = blockIdx.x * 256 + threadIdx.x;
    const int NT = 2048 * 256;

    // job A: dil_w transpose -> wT (bf16), k = tap*256+ci
    for (int u = g0; u < 8 * 512 * 32; u += NT) {
        int j = u & 31;
        int cog = u >> 5;
        const float* src = dil_w + ((size_t)cog << 9) + (j << 4);
        float4 a = *(const float4*)(src);
        float4 b = *(const float4*)(src + 4);
        float4 c = *(const float4*)(src + 8);
        float4 d = *(const float4*)(src + 12);
        bf16x8 t0 = {(__bf16)a.x, (__bf16)a.z, (__bf16)b.x, (__bf16)b.z,
                     (__bf16)c.x, (__bf16)c.z, (__bf16)d.x, (__bf16)d.z};
        bf16x8 t1 = {(__bf16)a.y, (__bf16)a.w, (__bf16)b.y, (__bf16)b.w,
                     (__bf16)c.y, (__bf16)c.w, (__bf16)d.y, (__bf16)d.w};
        *(bf16x8*)(wT + ((size_t)cog << 9) + (j << 3)) = t0;
        *(bf16x8*)(wT + ((size_t)cog << 9) + 256 + (j << 3)) = t1;
    }
    // job B: skip_w h-half cast -> w2[ly][co<256][ci] (bf16)
    for (int u = g0; u < 8 * 256 * 32; u += NT) {
        int row = u >> 5, j = u & 31;             // row = ly*256+co
        int ly = row >> 8, co = row & 255;
        const float* src = skip_w + (((size_t)(ly << 9) + co) << 8) + (j << 3);
        float4 a = *(const float4*)(src);
        float4 b = *(const float4*)(src + 4);
        bf16x8 v = {(__bf16)a.x, (__bf16)a.y, (__bf16)a.z, (__bf16)a.w,
                    (__bf16)b.x, (__bf16)b.y, (__bf16)b.z, (__bf16)b.w};
        *(bf16x8*)(w2 + ((size_t)row << 8) + (j << 3)) = v;
    }
    // job C: up-projection
    for (int u = g0; u < TBUF * NB * D; u += NT) {
        int row = u >> 8, c = u & 255;
        int tt = row >> 4, b = row & 15, t = T0 + tt;
        float acc = up_b[c] + x_lag[t * NB + b] * up_W[c];
        const float* cov = &x_cov[(t * NB + b) * 7];
        #pragma unroll
        for (int j = 0; j < 7; ++j)
            acc += cov[j] * up_W[(j + 1) * D + c];
        hf[u] = acc;
        hb[u] = (__bf16)acc;
    }
    // job D: vW partials (shallow chains, coalesced)
    for (int u = g0; u < 16384; u += NT) {
        int part = u >> 11;
        int r = u & 2047;
        int ly = r >> 8, ci = r & 255;
        const float* sw = skip_w + (((size_t)(ly << 9) + 256 + (part << 5)) << 8) + ci;
        float acc = 0.f;
        #pragma unroll 8
        for (int c = 0; c < 32; ++c)
            acc += sw[(size_t)c << 8] * loc_W[(part << 5) + c];
        vWp[u] = acc;
    }
}

// ---------------- GEMM1 narrow: grid (mt,8), BN=32, 16KB/buf -> 4 blocks/CU
// tail rows additionally saved to gsv (consumed by final_v2)
__global__ __launch_bounds__(512, 4) void gate_n32(
    const __bf16* __restrict__ hb, __bf16* __restrict__ gated,
    const __bf16* __restrict__ wTl, const float* __restrict__ gbias,
    __bf16* __restrict__ gsv, int do_save,
    int tb, int dil, int M)
{
    __shared__ __align__(16) unsigned char lds[32768];
    const int tid = threadIdx.x;
    const int lane = tid & 63, wid = tid >> 6;
    const int wm = wid >> 1, wn = wid & 1;
    const int l15 = lane & 15, l4 = lane >> 4;
    const int m0 = blockIdx.x << 6;
    const int cb = blockIdx.y << 5;               // 0..224
    const int arow = (wid << 3) + (lane >> 3);    // 0..63
    const int ach = lane & 7;
    const int aswz = (ach ^ (arow & 7)) << 3;
    const int bwid = wid & 3, bhalf = wid >> 2;   // 4 waves per B half
    const int brow = (bwid << 3) + (lane >> 3);   // 0..31
    const int bswz = (ach ^ (brow & 7)) << 3;
    const int roff1 = (tb - T0) * 16;
    const int roff0 = roff1 - dil * 16;

    f32x4 accf = {}, accg = {};

    auto stage = [&](int t, int buf) {
        const int k0 = t << 6;
        const int ci0 = k0 & 255;
        const int roff = (t < 4) ? roff0 : roff1;
        unsigned char* base = lds + buf * 16384;
        int m = m0 + arow; if (m >= M) m = M - 1;
        gload_lds16(hb + (size_t)(m + roff) * 256 + ci0 + aswz,
                    base + (wid << 10));
        gload_lds16(wTl + (size_t)(cb + bhalf * 256 + brow) * 512 + k0 + bswz,
                    base + 8192 + (bhalf << 12) + (bwid << 10));
    };

    stage(0, 0);
    for (int t = 0; t < 8; ++t) {
        const int buf = t & 1;
        if (t < 7) {
            stage(t + 1, buf ^ 1);
            asm volatile("s_waitcnt vmcnt(2)" ::: "memory");
        } else {
            asm volatile("s_waitcnt vmcnt(0)" ::: "memory");
        }
        __builtin_amdgcn_s_barrier();
        const unsigned char* base = lds + buf * 16384;
        __builtin_amdgcn_s_setprio(1);
        #pragma unroll
        for (int ks = 0; ks < 2; ++ks) {
            const int kb = (ks << 6) + (l4 << 4);
            int r = (wm << 4) + l15;
            bf16x8 av = *(const bf16x8*)(base + r * 128 + (kb ^ ((r & 7) << 4)));
            int n = (wn << 4) + l15;
            int o = n * 128 + (kb ^ ((n & 7) << 4));
            bf16x8 bfv = *(const bf16x8*)(base + 8192 + o);
            bf16x8 bgv = *(const bf16x8*)(base + 12288 + o);
            accf = __builtin_amdgcn_mfma_f32_16x16x32_bf16(av, bfv, accf, 0, 0, 0);
            accg = __builtin_amdgcn_mfma_f32_16x16x32_bf16(av, bgv, accg, 0, 0, 0);
        }
        __builtin_amdgcn_s_setprio(0);
        __builtin_amdgcn_s_barrier();
    }

    {
        const int ms0 = (TSKIP - tb) * 16;
        const int soff = (tb - TSKIP) * 16;
        int c = cb + (wn << 4) + l15;
        float bfb = gbias[c], bgb = gbias[c + 256];
        #pragma unroll
        for (int r = 0; r < 4; ++r) {
            int m = m0 + (wm << 4) + (l4 << 2) + r;
            if (m < M) {
                float fv = accf[r] + bfb;
                float gv = accg[r] + bgb;
                float th = 2.0f / (1.0f + __expf(-2.0f * fv)) - 1.0f;
                float sg = 1.0f / (1.0f + __expf(-gv));
                __bf16 val = (__bf16)(th * sg);
                gated[(size_t)m * 256 + c] = val;
                if (do_save && m >= ms0)
                    gsv[(size_t)(m + soff) * 256 + c] = val;
            }
        }
    }
}

// ---------------- GEMM2 h-only: grid (mt,8), BN=32, 12KB/buf
__global__ __launch_bounds__(512, 4) void skip_h(
    const __bf16* __restrict__ gated, const __bf16* __restrict__ w2l,
    float* __restrict__ hf, __bf16* __restrict__ hb,
    const float* __restrict__ sbias, int tb, int M)
{
    __shared__ __align__(16) unsigned char lds[24576];
    const int tid = threadIdx.x;
    const int lane = tid & 63, wid = tid >> 6;
    const int wm = wid >> 1, wn = wid & 1;
    const int l15 = lane & 15, l4 = lane >> 4;
    const int m0 = blockIdx.x << 6;
    const int cb = blockIdx.y << 5;
    const int arow = (wid << 3) + (lane >> 3);
    const int ach = lane & 7;
    const int aswz = (ach ^ (arow & 7)) << 3;
    const int brow = (wid << 3) + (lane >> 3);    // valid for wid<4
    const int bswz = (ach ^ (brow & 7)) << 3;
    const int roff1 = (tb - T0) * 16;

    f32x4 acch = {};

    auto stage = [&](int t, int buf) {
        const int k0 = t << 6;
        unsigned char* base = lds + buf * 12288;
        int m = m0 + arow; if (m >= M) m = M - 1;
        gload_lds16(gated + (size_t)m * 256 + k0 + aswz,
                    base + (wid << 10));
        if (wid < 4)
            gload_lds16(w2l + (size_t)(cb + brow) * 256 + k0 + bswz,
                        base + 8192 + (wid << 10));
    };

    stage(0, 0);
    for (int t = 0; t < 4; ++t) {
        const int buf = t & 1;
        if (t < 3) {
            stage(t + 1, buf ^ 1);
            if (wid < 4) { asm volatile("s_waitcnt vmcnt(2)" ::: "memory"); }
            else         { asm volatile("s_waitcnt vmcnt(1)" ::: "memory"); }
        } else {
            asm volatile("s_waitcnt vmcnt(0)" ::: "memory");
        }
        __builtin_amdgcn_s_barrier();
        const unsigned char* base = lds + buf * 12288;
        __builtin_amdgcn_s_setprio(1);
        #pragma unroll
        for (int ks = 0; ks < 2; ++ks) {
            const int kb = (ks << 6) + (l4 << 4);
            int r = (wm << 4) + l15;
            bf16x8 av = *(const bf16x8*)(base + r * 128 + (kb ^ ((r & 7) << 4)));
            int n = (wn << 4) + l15;
            int o = n * 128 + (kb ^ ((n & 7) << 4));
            bf16x8 bhv = *(const bf16x8*)(base + 8192 + o);
            acch = __builtin_amdgcn_mfma_f32_16x16x32_bf16(av, bhv, acch, 0, 0, 0);
        }
        __builtin_amdgcn_s_setprio(0);
        __builtin_amdgcn_s_barrier();
    }

    {
        int c = cb + (wn << 4) + l15;
        float bhb = sbias[c];
        #pragma unroll
        for (int r = 0; r < 4; ++r) {
            int m = m0 + (wm << 4) + (l4 << 2) + r;
            if (m < M) {
                size_t hi = (size_t)(m + roff1) * 256 + c;
                float hv = hf[hi] + acch[r] + bhb;
                hf[hi] = hv;
                hb[hi] = (__bf16)hv;
            }
        }
    }
}

// ---------------- final: out = (sum_l gated_l . vW_l + Cs + loc_b)*projW + proj_b
__global__ __launch_bounds__(256) void final_v2(
    const __bf16* __restrict__ gsave, const __bf16* __restrict__ gated,
    const float* __restrict__ vWp, const float* __restrict__ skip_b,
    const float* __restrict__ loc_W, const float* __restrict__ loc_b,
    const float* __restrict__ proj_W, const float* __restrict__ proj_b,
    float* __restrict__ out)
{
    int tid = threadIdx.x;
    int wid = tid >> 6, lane = tid & 63;
    int o = blockIdx.x * 4 + wid;        // o = (t - TSKIP)*16 + b
    float acc = 0.f;
    #pragma unroll
    for (int ly = 0; ly < 8; ++ly) {
        const __bf16* g = (ly < 7) ? gsave + (((size_t)ly * 1536 + o) << 8)
                                   : gated + ((size_t)o << 8);
        bf16x4v gv = *(const bf16x4v*)(g + (lane << 2));
        float4 vw = {0.f, 0.f, 0.f, 0.f};
        #pragma unroll
        for (int p = 0; p < 8; ++p) {
            float4 vp = *(const float4*)(vWp + (p << 11) + (ly << 8) + (lane << 2));
            vw.x += vp.x; vw.y += vp.y; vw.z += vp.z; vw.w += vp.w;
        }
        acc += (float)gv[0] * vw.x + (float)gv[1] * vw.y
             + (float)gv[2] * vw.z + (float)gv[3] * vw.w;
    }
    // skip-bias contribution: sum_{ly,c} skip_b[ly][256+c]*loc_W[c]
    #pragma unroll
    for (int j = 0; j < 32; ++j) {
        int idx = lane + (j << 6);
        int ly = idx >> 8, c = idx & 255;
        acc += skip_b[(ly << 9) + 256 + c] * loc_W[c];
    }
    #pragma unroll
    for (int off = 32; off; off >>= 1) acc += __shfl_down(acc, off);
    if (lane == 0) {
        int l = o >> 4, b = o & 15;
        out[b * LOUT + l] = (acc + loc_b[0]) * proj_W[0] + proj_b[0];
    }
}

extern "C" void kernel_launch(void* const* d_in, const int* in_sizes, int n_in,
                              void* d_out, int out_size, void* d_ws, size_t ws_size,
                              hipStream_t stream)
{
    const float* x_lag  = (const float*)d_in[0];
    const float* x_cov  = (const float*)d_in[1];
    const float* up_W   = (const float*)d_in[2];
    const float* up_b   = (const float*)d_in[3];
    const float* dil_w  = (const float*)d_in[4];
    const float* dil_b  = (const float*)d_in[5];
    const float* skip_w = (const float*)d_in[6];
    const float* skip_b = (const float*)d_in[7];
    const float* loc_W  = (const float*)d_in[8];
    const float* loc_b  = (const float*)d_in[9];
    const float* proj_W = (const float*)d_in[10];
    const float* proj_b = (const float*)d_in[11];
    float* out = (float*)d_out;

    unsigned char* ws = (unsigned char*)d_ws;
    float*  hf    = (float*)ws;                               // 5,767,168
    __bf16* hb    = (__bf16*)(ws + 5767168);                  // 2,883,584
    __bf16* gated = (__bf16*)(ws + 8650752);                  // 2,883,584
    __bf16* gsave = (__bf16*)(ws + 11534336);                 // 5,505,024
    __bf16* wT    = (__bf16*)(ws + 17039360);                 // 4,194,304
    __bf16* w2    = (__bf16*)(ws + 21233664);                 // 1,048,576 (h-half only)
    float*  vWp   = (float*)(ws + 22282240);                  // 65,536

    hipLaunchKernelGGL(prep_up, dim3(2048), dim3(256), 0, stream,
                       dil_w, skip_w, x_lag, x_cov, up_W, up_b, loc_W,
                       wT, w2, hf, hb, vWp);

    for (int i = 0; i < 8; ++i) {
        int dil = 1 << i;
        int tb  = T0 + 2 * dil;
        int M   = (T_TOTAL - tb) * NB;
        int mt  = (M + 63) >> 6;
        const __bf16* wTl = wT + (size_t)i * 512 * 512;
        const __bf16* w2l = w2 + (size_t)i * 256 * 256;
        const float* gb = dil_b + (size_t)i * 512;
        const float* sb = skip_b + (size_t)i * 512;

        hipLaunchKernelGGL(gate_n32, dim3(mt, 8), dim3(512), 0, stream,
                           hb, gated, wTl, gb,
                           gsave + (size_t)i * 1536 * 256, i < 7 ? 1 : 0,
                           tb, dil, M);
        if (i < 7)
            hipLaunchKernelGGL(skip_h, dim3(mt, 8), dim3(512), 0, stream,
                               gated, w2l, hf, hb, sb, tb, M);
    }
    hipLaunchKernelGGL(final_v2, dim3(LOUT * NB / 4), dim3(256), 0, stream,
                       gsave, gated, vWp, skip_b, loc_W, loc_b, proj_W, proj_b,
                       out);
}

// Round 15
// 123.642 us; speedup vs baseline: 1.1856x; 1.0618x over previous
//
#include <hip/hip_runtime.h>
#include <math.h>
#include <stdint.h>

#define T_TOTAL 2048
#define NB 16
#define D 256
#define T0 1696      // h buffer covers t in [1696, 2047]
#define TBUF 352
#define TSKIP 1952   // output rows t in [1952, 2047]
#define LOUT 96

typedef __bf16 bf16x8 __attribute__((ext_vector_type(8)));
typedef __bf16 bf16x4v __attribute__((ext_vector_type(4)));
typedef float f32x4 __attribute__((ext_vector_type(4)));

__device__ __forceinline__ void gload_lds16(const void* src, void* lds_dst) {
    auto g = (const __attribute__((address_space(1))) void*)(uintptr_t)src;
    auto l = (__attribute__((address_space(3))) void*)(uintptr_t)(
                 (uint32_t)(uintptr_t)lds_dst);
    __builtin_amdgcn_global_load_lds(g, l, 16, 0, 0);
}

// XCD-grouped decode: grid = mtp*8 (mtp%8==0). id%8 = XCD (dispatch round-robin
// heuristic); each XCD owns a contiguous chunk of row-tiles; all 8 col-tiles of
// a row-tile stay on one XCD -> A-panel fetched into one L2 only.
__device__ __forceinline__ void decode_tile(int id, int gridx, int& rt, int& ct) {
    int k = id & 7;
    int j = id >> 3;
    int rpx = gridx >> 6;          // mtp/8 row-tiles per XCD
    rt = k * rpx + (j >> 3);
    ct = j & 7;
}

// ---------------- fused weight prep + up-projection + vW partials
__global__ __launch_bounds__(256) void prep_up(
    const float* __restrict__ dil_w, const float* __restrict__ skip_w,
    const float* __restrict__ x_lag, const float* __restrict__ x_cov,
    const float* __restrict__ up_W, const float* __restrict__ up_b,
    const float* __restrict__ loc_W,
    __bf16* __restrict__ wT, __bf16* __restrict__ w2,
    float* __restrict__ hf, __bf16* __restrict__ hb,
    float* __restrict__ vWp)
{
    const int g0 = blockIdx.x * 256 + threadIdx.x;
    const int NT = 2048 * 256;

    for (int u = g0; u < 8 * 512 * 32; u += NT) {
        int j = u & 31;
        int cog = u >> 5;
        const float* src = dil_w + ((size_t)cog << 9) + (j << 4);
        float4 a = *(const float4*)(src);
        float4 b = *(const float4*)(src + 4);
        float4 c = *(const float4*)(src + 8);
        float4 d = *(const float4*)(src + 12);
        bf16x8 t0 = {(__bf16)a.x, (__bf16)a.z, (__bf16)b.x, (__bf16)b.z,
                     (__bf16)c.x, (__bf16)c.z, (__bf16)d.x, (__bf16)d.z};
        bf16x8 t1 = {(__bf16)a.y, (__bf16)a.w, (__bf16)b.y, (__bf16)b.w,
                     (__bf16)c.y, (__bf16)c.w, (__bf16)d.y, (__bf16)d.w};
        *(bf16x8*)(wT + ((size_t)cog << 9) + (j << 3)) = t0;
        *(bf16x8*)(wT + ((size_t)cog << 9) + 256 + (j << 3)) = t1;
    }
    for (int u = g0; u < 8 * 256 * 32; u += NT) {
        int row = u >> 5, j = u & 31;             // row = ly*256+co
        int ly = row >> 8, co = row & 255;
        const float* src = skip_w + (((size_t)(ly << 9) + co) << 8) + (j << 3);
        float4 a = *(const float4*)(src);
        float4 b = *(const float4*)(src + 4);
        bf16x8 v = {(__bf16)a.x, (__bf16)a.y, (__bf16)a.z, (__bf16)a.w,
                    (__bf16)b.x, (__bf16)b.y, (__bf16)b.z, (__bf16)b.w};
        *(bf16x8*)(w2 + ((size_t)row << 8) + (j << 3)) = v;
    }
    for (int u = g0; u < TBUF * NB * D; u += NT) {
        int row = u >> 8, c = u & 255;
        int tt = row >> 4, b = row & 15, t = T0 + tt;
        float acc = up_b[c] + x_lag[t * NB + b] * up_W[c];
        const float* cov = &x_cov[(t * NB + b) * 7];
        #pragma unroll
        for (int j = 0; j < 7; ++j)
            acc += cov[j] * up_W[(j + 1) * D + c];
        hf[u] = acc;
        hb[u] = (__bf16)acc;
    }
    for (int u = g0; u < 16384; u += NT) {
        int part = u >> 11;
        int r = u & 2047;
        int ly = r >> 8, ci = r & 255;
        const float* sw = skip_w + (((size_t)(ly << 9) + 256 + (part << 5)) << 8) + ci;
        float acc = 0.f;
        #pragma unroll 8
        for (int c = 0; c < 32; ++c)
            acc += sw[(size_t)c << 8] * loc_W[(part << 5) + c];
        vWp[u] = acc;
    }
}

// ---------------- GEMM1 narrow: 1-D grid mtp*8, XCD-grouped, BN=32
__global__ __launch_bounds__(512, 4) void gate_n32(
    const __bf16* __restrict__ hb, __bf16* __restrict__ gated,
    const __bf16* __restrict__ wTl, const float* __restrict__ gbias,
    __bf16* __restrict__ gsv, int do_save,
    int tb, int dil, int M)
{
    __shared__ __align__(16) unsigned char lds[32768];
    int rt, ct;
    decode_tile(blockIdx.x, gridDim.x, rt, ct);
    const int m0 = rt << 6;
    if (m0 >= M) return;                          // padded row-tiles (block-uniform)
    const int cb = ct << 5;                       // 0..224
    const int tid = threadIdx.x;
    const int lane = tid & 63, wid = tid >> 6;
    const int wm = wid >> 1, wn = wid & 1;
    const int l15 = lane & 15, l4 = lane >> 4;
    const int arow = (wid << 3) + (lane >> 3);    // 0..63
    const int ach = lane & 7;
    const int aswz = (ach ^ (arow & 7)) << 3;
    const int bwid = wid & 3, bhalf = wid >> 2;   // 4 waves per B half
    const int brow = (bwid << 3) + (lane >> 3);   // 0..31
    const int bswz = (ach ^ (brow & 7)) << 3;
    const int roff1 = (tb - T0) * 16;
    const int roff0 = roff1 - dil * 16;

    f32x4 accf = {}, accg = {};

    auto stage = [&](int t, int buf) {
        const int k0 = t << 6;
        const int ci0 = k0 & 255;
        const int roff = (t < 4) ? roff0 : roff1;
        unsigned char* base = lds + buf * 16384;
        int m = m0 + arow; if (m >= M) m = M - 1;
        gload_lds16(hb + (size_t)(m + roff) * 256 + ci0 + aswz,
                    base + (wid << 10));
        gload_lds16(wTl + (size_t)(cb + bhalf * 256 + brow) * 512 + k0 + bswz,
                    base + 8192 + (bhalf << 12) + (bwid << 10));
    };

    stage(0, 0);
    for (int t = 0; t < 8; ++t) {
        const int buf = t & 1;
        if (t < 7) {
            stage(t + 1, buf ^ 1);
            asm volatile("s_waitcnt vmcnt(2)" ::: "memory");
        } else {
            asm volatile("s_waitcnt vmcnt(0)" ::: "memory");
        }
        __builtin_amdgcn_s_barrier();
        const unsigned char* base = lds + buf * 16384;
        __builtin_amdgcn_s_setprio(1);
        #pragma unroll
        for (int ks = 0; ks < 2; ++ks) {
            const int kb = (ks << 6) + (l4 << 4);
            int r = (wm << 4) + l15;
            bf16x8 av = *(const bf16x8*)(base + r * 128 + (kb ^ ((r & 7) << 4)));
            int n = (wn << 4) + l15;
            int o = n * 128 + (kb ^ ((n & 7) << 4));
            bf16x8 bfv = *(const bf16x8*)(base + 8192 + o);
            bf16x8 bgv = *(const bf16x8*)(base + 12288 + o);
            accf = __builtin_amdgcn_mfma_f32_16x16x32_bf16(av, bfv, accf, 0, 0, 0);
            accg = __builtin_amdgcn_mfma_f32_16x16x32_bf16(av, bgv, accg, 0, 0, 0);
        }
        __builtin_amdgcn_s_setprio(0);
        __builtin_amdgcn_s_barrier();
    }

    {
        const int ms0 = (TSKIP - tb) * 16;
        const int soff = (tb - TSKIP) * 16;
        int c = cb + (wn << 4) + l15;
        float bfb = gbias[c], bgb = gbias[c + 256];
        #pragma unroll
        for (int r = 0; r < 4; ++r) {
            int m = m0 + (wm << 4) + (l4 << 2) + r;
            if (m < M) {
                float fv = accf[r] + bfb;
                float gv = accg[r] + bgb;
                float th = 2.0f / (1.0f + __expf(-2.0f * fv)) - 1.0f;
                float sg = 1.0f / (1.0f + __expf(-gv));
                __bf16 val = (__bf16)(th * sg);
                gated[(size_t)m * 256 + c] = val;
                if (do_save && m >= ms0)
                    gsv[(size_t)(m + soff) * 256 + c] = val;
            }
        }
    }
}

// ---------------- GEMM2 h-only: 1-D grid mtp*8, XCD-grouped, BN=32
__global__ __launch_bounds__(512, 4) void skip_h(
    const __bf16* __restrict__ gated, const __bf16* __restrict__ w2l,
    float* __restrict__ hf, __bf16* __restrict__ hb,
    const float* __restrict__ sbias, int tb, int M)
{
    __shared__ __align__(16) unsigned char lds[24576];
    int rt, ct;
    decode_tile(blockIdx.x, gridDim.x, rt, ct);
    const int m0 = rt << 6;
    if (m0 >= M) return;
    const int cb = ct << 5;
    const int tid = threadIdx.x;
    const int lane = tid & 63, wid = tid >> 6;
    const int wm = wid >> 1, wn = wid & 1;
    const int l15 = lane & 15, l4 = lane >> 4;
    const int arow = (wid << 3) + (lane >> 3);
    const int ach = lane & 7;
    const int aswz = (ach ^ (arow & 7)) << 3;
    const int brow = (wid << 3) + (lane >> 3);    // valid for wid<4
    const int bswz = (ach ^ (brow & 7)) << 3;
    const int roff1 = (tb - T0) * 16;

    f32x4 acch = {};

    auto stage = [&](int t, int buf) {
        const int k0 = t << 6;
        unsigned char* base = lds + buf * 12288;
        int m = m0 + arow; if (m >= M) m = M - 1;
        gload_lds16(gated + (size_t)m * 256 + k0 + aswz,
                    base + (wid << 10));
        if (wid < 4)
            gload_lds16(w2l + (size_t)(cb + brow) * 256 + k0 + bswz,
                        base + 8192 + (wid << 10));
    };

    stage(0, 0);
    for (int t = 0; t < 4; ++t) {
        const int buf = t & 1;
        if (t < 3) {
            stage(t + 1, buf ^ 1);
            if (wid < 4) { asm volatile("s_waitcnt vmcnt(2)" ::: "memory"); }
            else         { asm volatile("s_waitcnt vmcnt(1)" ::: "memory"); }
        } else {
            asm volatile("s_waitcnt vmcnt(0)" ::: "memory");
        }
        __builtin_amdgcn_s_barrier();
        const unsigned char* base = lds + buf * 12288;
        __builtin_amdgcn_s_setprio(1);
        #pragma unroll
        for (int ks = 0; ks < 2; ++ks) {
            const int kb = (ks << 6) + (l4 << 4);
            int r = (wm << 4) + l15;
            bf16x8 av = *(const bf16x8*)(base + r * 128 + (kb ^ ((r & 7) << 4)));
            int n = (wn << 4) + l15;
            int o = n * 128 + (kb ^ ((n & 7) << 4));
            bf16x8 bhv = *(const bf16x8*)(base + 8192 + o);
            acch = __builtin_amdgcn_mfma_f32_16x16x32_bf16(av, bhv, acch, 0, 0, 0);
        }
        __builtin_amdgcn_s_setprio(0);
        __builtin_amdgcn_s_barrier();
    }

    {
        int c = cb + (wn << 4) + l15;
        float bhb = sbias[c];
        #pragma unroll
        for (int r = 0; r < 4; ++r) {
            int m = m0 + (wm << 4) + (l4 << 2) + r;
            if (m < M) {
                size_t hi = (size_t)(m + roff1) * 256 + c;
                float hv = hf[hi] + acch[r] + bhb;
                hf[hi] = hv;
                hb[hi] = (__bf16)hv;
            }
        }
    }
}

// ---------------- final: out = (sum_l gated_l . vW_l + Cs + loc_b)*projW + proj_b
__global__ __launch_bounds__(256) void final_v2(
    const __bf16* __restrict__ gsave, const __bf16* __restrict__ gated,
    const float* __restrict__ vWp, const float* __restrict__ skip_b,
    const float* __restrict__ loc_W, const float* __restrict__ loc_b,
    const float* __restrict__ proj_W, const float* __restrict__ proj_b,
    float* __restrict__ out)
{
    int tid = threadIdx.x;
    int wid = tid >> 6, lane = tid & 63;
    int o = blockIdx.x * 4 + wid;        // o = (t - TSKIP)*16 + b
    float acc = 0.f;
    #pragma unroll
    for (int ly = 0; ly < 8; ++ly) {
        const __bf16* g = (ly < 7) ? gsave + (((size_t)ly * 1536 + o) << 8)
                                   : gated + ((size_t)o << 8);
        bf16x4v gv = *(const bf16x4v*)(g + (lane << 2));
        float4 vw = {0.f, 0.f, 0.f, 0.f};
        #pragma unroll
        for (int p = 0; p < 8; ++p) {
            float4 vp = *(const float4*)(vWp + (p << 11) + (ly << 8) + (lane << 2));
            vw.x += vp.x; vw.y += vp.y; vw.z += vp.z; vw.w += vp.w;
        }
        acc += (float)gv[0] * vw.x + (float)gv[1] * vw.y
             + (float)gv[2] * vw.z + (float)gv[3] * vw.w;
    }
    #pragma unroll
    for (int j = 0; j < 32; ++j) {
        int idx = lane + (j << 6);
        int ly = idx >> 8, c = idx & 255;
        acc += skip_b[(ly << 9) + 256 + c] * loc_W[c];
    }
    #pragma unroll
    for (int off = 32; off; off >>= 1) acc += __shfl_down(acc, off);
    if (lane == 0) {
        int l = o >> 4, b = o & 15;
        out[b * LOUT + l] = (acc + loc_b[0]) * proj_W[0] + proj_b[0];
    }
}

extern "C" void kernel_launch(void* const* d_in, const int* in_sizes, int n_in,
                              void* d_out, int out_size, void* d_ws, size_t ws_size,
                              hipStream_t stream)
{
    const float* x_lag  = (const float*)d_in[0];
    const float* x_cov  = (const float*)d_in[1];
    const float* up_W   = (const float*)d_in[2];
    const float* up_b   = (const float*)d_in[3];
    const float* dil_w  = (const float*)d_in[4];
    const float* dil_b  = (const float*)d_in[5];
    const float* skip_w = (const float*)d_in[6];
    const float* skip_b = (const float*)d_in[7];
    const float* loc_W  = (const float*)d_in[8];
    const float* loc_b  = (const float*)d_in[9];
    const float* proj_W = (const float*)d_in[10];
    const float* proj_b = (const float*)d_in[11];
    float* out = (float*)d_out;

    unsigned char* ws = (unsigned char*)d_ws;
    float*  hf    = (float*)ws;                               // 5,767,168
    __bf16* hb    = (__bf16*)(ws + 5767168);                  // 2,883,584
    __bf16* gated = (__bf16*)(ws + 8650752);                  // 2,883,584
    __bf16* gsave = (__bf16*)(ws + 11534336);                 // 5,505,024
    __bf16* wT    = (__bf16*)(ws + 17039360);                 // 4,194,304
    __bf16* w2    = (__bf16*)(ws + 21233664);                 // 1,048,576
    float*  vWp   = (float*)(ws + 22282240);                  // 65,536

    hipLaunchKernelGGL(prep_up, dim3(2048), dim3(256), 0, stream,
                       dil_w, skip_w, x_lag, x_cov, up_W, up_b, loc_W,
                       wT, w2, hf, hb, vWp);

    for (int i = 0; i < 8; ++i) {
        int dil = 1 << i;
        int tb  = T0 + 2 * dil;
        int M   = (T_TOTAL - tb) * NB;
        int mt  = (M + 63) >> 6;
        int mtp = (mt + 7) & ~7;                  // pad to %8 for XCD decode
        const __bf16* wTl = wT + (size_t)i * 512 * 512;
        const __bf16* w2l = w2 + (size_t)i * 256 * 256;
        const float* gb = dil_b + (size_t)i * 512;
        const float* sb = skip_b + (size_t)i * 512;

        hipLaunchKernelGGL(gate_n32, dim3(mtp * 8), dim3(512), 0, stream,
                           hb, gated, wTl, gb,
                           gsave + (size_t)i * 1536 * 256, i < 7 ? 1 : 0,
                           tb, dil, M);
        if (i < 7)
            hipLaunchKernelGGL(skip_h, dim3(mtp * 8), dim3(512), 0, stream,
                               gated, w2l, hf, hb, sb, tb, M);
    }
    hipLaunchKernelGGL(final_v2, dim3(LOUT * NB / 4), dim3(256), 0, stream,
                       gsave, gated, vWp, skip_b, loc_W, loc_b, proj_W, proj_b,
                       out);
}